// Round 5
// baseline (392.350 us; speedup 1.0000x reference)
//
#include <hip/hip_runtime.h>

// ---------------------------------------------------------------------------
// Swin block: LN1 -> shift+window -> QKV -> win-attn(+relbias+mask) -> proj
//             -> reverse+residual -> LN2 -> fused MLP (GEMM1+GELU+GEMM2+resid)
// B=16 H=W=64 C=256 WS=8 SHIFT=4 HEADS=8 HD=32 N=64 HID=1024
// Round 4: (a) MLP1+MLP2 fused into one kernel (hidden never leaves the CU:
//          A 64x256 staged once, per-128-chunk GEMM1->gelu->H_lds->GEMM2,
//          saves 256MB HBM + the gelu/scatter epilogue). (b) involutive XOR
//          LDS swizzle with pre-swizzled global_load_lds sources everywhere.
// ---------------------------------------------------------------------------

typedef __attribute__((ext_vector_type(8))) short bf16x8;
typedef __attribute__((ext_vector_type(4))) float f32x4;
typedef __attribute__((ext_vector_type(16))) float f32x16;

__device__ __forceinline__ float bf2f(unsigned short h) {
    union { unsigned int u; float f; } c; c.u = ((unsigned int)h) << 16; return c.f;
}
__device__ __forceinline__ unsigned short f2bf(float f) {
    union { float f; unsigned int u; } c; c.f = f;
    unsigned int u = c.u;
    return (unsigned short)((u + 0x7FFFu + ((u >> 16) & 1u)) >> 16);
}
__device__ __forceinline__ unsigned int cvtpk_bf16(float lo, float hi) {
    unsigned int r;
    asm volatile("v_cvt_pk_bf16_f32 %0, %1, %2" : "=v"(r) : "v"(lo), "v"(hi));
    return r;
}
__device__ __forceinline__ void perm32swap(unsigned int& a, unsigned int& b) {
    asm volatile("v_permlane32_swap_b32 %0, %1" : "+v"(a), "+v"(b));
}
// window-order row (b, wi, wj, r, cc) -> pixel-order row (b, hp, wp).
__device__ __forceinline__ int remap_row(int row) {
    int b  = row >> 12;
    int w6 = (row >> 6) & 63;
    int n  = row & 63;
    int hp = (((w6 >> 3) << 3) + (n >> 3) + 4) & 63;
    int wp = (((w6 & 7) << 3) + (n & 7) + 4) & 63;
    return (b << 12) | (hp << 6) | wp;
}
// gelu(v) = v * sigmoid(2c(v + 0.044715 v^3)), c = sqrt(2/pi)
__device__ __forceinline__ float gelu_f(float v) {
    float u = 1.5957691216057308f * (v + 0.044715f * v * v * v);
    return v / (1.0f + __expf(-u));
}
__device__ __forceinline__ void gload16(const unsigned short* g, unsigned short* l) {
    __builtin_amdgcn_global_load_lds(
        (const __attribute__((address_space(1))) void*)g,
        (__attribute__((address_space(3))) void*)l, 16, 0, 0);
}

// ---- LayerNorm over C=256; one wave per row; optional gather remap --------
__global__ __launch_bounds__(256) void ln_kernel(
    const float* __restrict__ in, const float* __restrict__ g,
    const float* __restrict__ b, unsigned short* __restrict__ out, int remap)
{
    int wave = threadIdx.x >> 6, lane = threadIdx.x & 63;
    int row = (blockIdx.x << 2) + wave;
    int src = remap ? remap_row(row) : row;
    float4 xv = *(const float4*)(in + (size_t)src * 256 + (lane << 2));
    float s  = xv.x + xv.y + xv.z + xv.w;
    float ss = xv.x*xv.x + xv.y*xv.y + xv.z*xv.z + xv.w*xv.w;
#pragma unroll
    for (int off = 32; off; off >>= 1) {
        s  += __shfl_xor(s,  off, 64);
        ss += __shfl_xor(ss, off, 64);
    }
    float mu  = s * (1.0f / 256.0f);
    float inv = rsqrtf(ss * (1.0f / 256.0f) - mu * mu + 1e-5f);
    float4 gv = *(const float4*)(g + (lane << 2));
    float4 bv = *(const float4*)(b + (lane << 2));
    ushort4 o;
    o.x = f2bf((xv.x - mu) * inv * gv.x + bv.x);
    o.y = f2bf((xv.y - mu) * inv * gv.y + bv.y);
    o.z = f2bf((xv.z - mu) * inv * gv.z + bv.z);
    o.w = f2bf((xv.w - mu) * inv * gv.w + bv.w);
    *(ushort4*)(out + (size_t)row * 256 + (lane << 2)) = o;
}

// ---- expand rel-pos bias to [head][q][key] f32 -----------------------------
__global__ __launch_bounds__(256) void bias_expand_kernel(
    const float* __restrict__ table, const int* __restrict__ relidx,
    float* __restrict__ out)
{
    int i = blockIdx.x * 256 + threadIdx.x;
    int head = i >> 12;
    int q = (i >> 6) & 63;
    int k = i & 63;
    out[i] = table[relidx[q * 64 + k] * 8 + head];
}

// ---- weight convert: f32 [K,N] -> bf16 [N,K] (transposed) -----------------
__global__ __launch_bounds__(256) void convert_T_kernel(
    const float* __restrict__ in, unsigned short* __restrict__ out, int K, int N)
{
    __shared__ float t[32][33];
    int kb = K >> 5;
    int bk = (blockIdx.x % kb) << 5;
    int bn = (blockIdx.x / kb) << 5;
    int r = threadIdx.x >> 5, c = threadIdx.x & 31;
#pragma unroll
    for (int i = 0; i < 4; ++i)
        t[r + i * 8][c] = in[(size_t)(bk + r + i * 8) * N + bn + c];
    __syncthreads();
#pragma unroll
    for (int i = 0; i < 4; ++i)
        out[(size_t)(bn + r + i * 8) * K + bk + c] = f2bf(t[c][r + i * 8]);
}

// ---- MFMA GEMM: A bf16 [M,K] row-major, BT bf16 [N,K] row-major -----------
// 128x128 tile, BK=32, dbuf prefetch, XCD swizzle, XOR-swizzled LDS.
template<int OUT_BF16, int DO_GELU, int RESID, int QSCALE>
__global__ __launch_bounds__(256) void mgemm_kernel(
    const unsigned short* __restrict__ A, const unsigned short* __restrict__ BT,
    const float* __restrict__ bias, void* __restrict__ outp,
    const float* __restrict__ resid, int M, int N, int K)
{
    __shared__ unsigned short As[2][128 * 32];
    __shared__ unsigned short Bs[2][128 * 32];

    const int cpx = (int)gridDim.x >> 3;
    const int bid = ((int)blockIdx.x & 7) * cpx + ((int)blockIdx.x >> 3);

    const int nb = N >> 7;
    const int m0 = (bid / nb) << 7;
    const int n0 = (bid % nb) << 7;
    const int tid  = threadIdx.x;
    const int wid  = tid >> 6;
    const int lane = tid & 63;
    const int wm = (wid >> 1) << 6;
    const int wn = (wid & 1) << 6;

    const unsigned short* Ag = A  + (size_t)m0 * K;
    const unsigned short* Bg = BT + (size_t)n0 * K;
    const int s0 = tid, s1 = tid + 256;
    // LDS slot s holds logical k-group (s&3)^(row&3): pre-swizzled source
    const size_t ra0 = (size_t)(s0 >> 2) * K + (((s0 & 3) ^ ((s0 >> 2) & 3)) << 3);
    const size_t ra1 = (size_t)(s1 >> 2) * K + (((s1 & 3) ^ ((s1 >> 2) & 3)) << 3);

    f32x4 acc[4][4] = {};
    const int fr = lane & 15;
    const int fq = lane >> 4;
    const int axor = ((fq ^ (fr & 3)) << 3);   // swizzled read offset (elements)

    gload16(Ag + ra0, As[0] + s0 * 8);
    gload16(Ag + ra1, As[0] + s1 * 8);
    gload16(Bg + ra0, Bs[0] + s0 * 8);
    gload16(Bg + ra1, Bs[0] + s1 * 8);
    __syncthreads();

    int cur = 0;
    for (int k0 = 0; k0 < K; k0 += 32) {
        if (k0 + 32 < K) {
            const int nxt = cur ^ 1;
            gload16(Ag + ra0 + k0 + 32, As[nxt] + s0 * 8);
            gload16(Ag + ra1 + k0 + 32, As[nxt] + s1 * 8);
            gload16(Bg + ra0 + k0 + 32, Bs[nxt] + s0 * 8);
            gload16(Bg + ra1 + k0 + 32, Bs[nxt] + s1 * 8);
        }

        bf16x8 af[4], bfr[4];
#pragma unroll
        for (int i = 0; i < 4; ++i)
            af[i] = *(const bf16x8*)(As[cur] + (wm + i * 16 + fr) * 32 + axor);
#pragma unroll
        for (int j = 0; j < 4; ++j)
            bfr[j] = *(const bf16x8*)(Bs[cur] + (wn + j * 16 + fr) * 32 + axor);
#pragma unroll
        for (int i = 0; i < 4; ++i)
#pragma unroll
            for (int j = 0; j < 4; ++j)
                acc[i][j] = __builtin_amdgcn_mfma_f32_16x16x32_bf16(
                    af[i], bfr[j], acc[i][j], 0, 0, 0);
        __syncthreads();
        cur ^= 1;
    }

#pragma unroll
    for (int i = 0; i < 4; ++i) {
#pragma unroll
        for (int j = 0; j < 4; ++j) {
            const int col = n0 + wn + j * 16 + (lane & 15);
            const float bv = bias[col];
#pragma unroll
            for (int v = 0; v < 4; ++v) {
                const int row = m0 + wm + i * 16 + ((lane >> 4) << 2) + v;
                float val = acc[i][j][v] + bv;
                if (QSCALE) { if (col < 256) val *= 0.17677669529663687f; }
                if (DO_GELU) val = gelu_f(val);
                if (OUT_BF16) {
                    ((unsigned short*)outp)[(size_t)row * N + col] = f2bf(val);
                } else {
                    const int orow = (RESID == 2) ? remap_row(row) : row;
                    const float r = RESID ? resid[(size_t)orow * N + col] : 0.0f;
                    ((float*)outp)[(size_t)orow * N + col] = r + val;
                }
            }
        }
    }
}

// ---- fused MLP: out = h2 + (gelu(ln2 @ w1 + b1)) @ w2 + b2 ----------------
// Per block: 64 rows. A 64x256 staged once; 8 chunks of 128 hidden units:
//   GEMM1 (BK=64, dbuf) -> gelu -> H_lds (16KB) -> GEMM2 (BK=32, dbuf) acc.
// 4 waves: GEMM1 n-split 4x32, GEMM2 n-split 4x64. LDS 80KB -> 2 blocks/CU.
__global__ __launch_bounds__(256) void mlp_fused_kernel(
    const unsigned short* __restrict__ A,    // ln2out bf16 [65536,256]
    const unsigned short* __restrict__ W1T,  // bf16 [1024,256]
    const float* __restrict__ b1v,
    const unsigned short* __restrict__ W2T,  // bf16 [256,1024]
    const float* __restrict__ b2v,
    const float* __restrict__ h2,            // f32 residual
    float* __restrict__ outp)                // f32 [65536,256]
{
    __shared__ unsigned short Al[64 * 256];  // 32KB, swz ^((row&7)<<3) elems
    __shared__ unsigned short Hl[64 * 128];  // 16KB, swz ^((row&7)<<3)
    __shared__ unsigned short Bsh[2][8192];  // 2x16KB: B1 [128][64] / B2 [256][32]

    const int m0 = (int)blockIdx.x << 6;
    const int tid = threadIdx.x;
    const int lane = tid & 63;
    const int wid = tid >> 6;
    const int fr = lane & 15, fq = lane >> 4;
    const int wn1 = wid << 5;                // GEMM1 hid-col offset
    const int wn2 = wid << 6;                // GEMM2 out-col offset

    // stage A [64][256]: slot s holds logical col-group (s&31)^(row&7)
#pragma unroll
    for (int i = 0; i < 8; ++i) {
        int s = tid + (i << 8);              // 0..2047
        int row = s >> 5;
        int ce = ((s & 31) ^ (row & 7)) << 3;
        gload16(A + (size_t)(m0 + row) * 256 + ce, Al + s * 8);
    }

#define STAGE_B1(c, t, buf)                                                   \
    {                                                                         \
        _Pragma("unroll")                                                     \
        for (int i_ = 0; i_ < 4; ++i_) {                                      \
            int s_ = tid + (i_ << 8);                                         \
            int r_ = s_ >> 3;                                                 \
            int ce_ = ((s_ & 7) ^ (r_ & 7)) << 3;                             \
            gload16(W1T + (size_t)((c) * 128 + r_) * 256 + (t) * 64 + ce_,    \
                    Bsh[buf] + s_ * 8);                                       \
        }                                                                     \
    }
#define STAGE_B2(c, t, buf)                                                   \
    {                                                                         \
        _Pragma("unroll")                                                     \
        for (int i_ = 0; i_ < 4; ++i_) {                                      \
            int s_ = tid + (i_ << 8);                                         \
            int r_ = s_ >> 2;                                                 \
            int ce_ = ((s_ & 3) ^ (r_ & 3)) << 3;                             \
            gload16(W2T + (size_t)r_ * 1024 + (c) * 128 + (t) * 32 + ce_,     \
                    Bsh[buf] + s_ * 8);                                       \
        }                                                                     \
    }

    f32x4 acc2[4][4] = {};
    STAGE_B1(0, 0, 0);
    __syncthreads();

    for (int c = 0; c < 8; ++c) {
        // ---- GEMM1: hidden[64 x 128] chunk, K=256 in 4 steps of 64 ----------
        f32x4 acc1[4][2] = {};
#pragma unroll
        for (int t = 0; t < 4; ++t) {
            if (t < 3) { STAGE_B1(c, t + 1, (t + 1) & 1); }
            else       { STAGE_B2(c, 0, 0); }
            bf16x8 a[4][2], b[2][2];
#pragma unroll
            for (int i = 0; i < 4; ++i) {
                int row = i * 16 + fr;
#pragma unroll
                for (int kk = 0; kk < 2; ++kk)
                    a[i][kk] = *(const bf16x8*)(Al + row * 256 +
                        ((t * 64 + kk * 32 + fq * 8) ^ ((row & 7) << 3)));
            }
#pragma unroll
            for (int j = 0; j < 2; ++j) {
                int row = wn1 + j * 16 + fr;
#pragma unroll
                for (int kk = 0; kk < 2; ++kk)
                    b[j][kk] = *(const bf16x8*)(Bsh[t & 1] + row * 64 +
                        ((kk * 32 + fq * 8) ^ ((row & 7) << 3)));
            }
#pragma unroll
            for (int i = 0; i < 4; ++i)
#pragma unroll
                for (int j = 0; j < 2; ++j)
#pragma unroll
                    for (int kk = 0; kk < 2; ++kk)
                        acc1[i][j] = __builtin_amdgcn_mfma_f32_16x16x32_bf16(
                            a[i][kk], b[j][kk], acc1[i][j], 0, 0, 0);
            __syncthreads();
        }
        // ---- gelu -> H_lds ---------------------------------------------------
#pragma unroll
        for (int j = 0; j < 2; ++j) {
            int col = wn1 + j * 16 + fr;
            float bv = b1v[c * 128 + col];
#pragma unroll
            for (int i = 0; i < 4; ++i)
#pragma unroll
                for (int v = 0; v < 4; ++v) {
                    int row = i * 16 + fq * 4 + v;
                    float val = gelu_f(acc1[i][j][v] + bv);
                    int lin = (row << 8) + (col << 1);
                    lin ^= (row & 7) << 4;
                    *(unsigned short*)((char*)Hl + lin) = f2bf(val);
                }
        }
        __syncthreads();   // H ready; B2(c,0) staged during GEMM1 t=3 also done
        // ---- GEMM2: acc2 += H[64x128] @ w2T-chunk, K=128 in 4 steps of 32 ----
#pragma unroll
        for (int t = 0; t < 4; ++t) {
            if (t < 3)      { STAGE_B2(c, t + 1, (t + 1) & 1); }
            else if (c < 7) { STAGE_B1(c + 1, 0, 0); }
            bf16x8 ha[4], bb[4];
#pragma unroll
            for (int i = 0; i < 4; ++i) {
                int row = i * 16 + fr;
                ha[i] = *(const bf16x8*)(Hl + row * 128 +
                    ((t * 32 + fq * 8) ^ ((row & 7) << 3)));
            }
#pragma unroll
            for (int j = 0; j < 4; ++j) {
                int row = wn2 + j * 16 + fr;
                bb[j] = *(const bf16x8*)(Bsh[t & 1] + row * 32 +
                    ((fq * 8) ^ ((row & 3) << 3)));
            }
#pragma unroll
            for (int i = 0; i < 4; ++i)
#pragma unroll
                for (int j = 0; j < 4; ++j)
                    acc2[i][j] = __builtin_amdgcn_mfma_f32_16x16x32_bf16(
                        ha[i], bb[j], acc2[i][j], 0, 0, 0);
            __syncthreads();
        }
    }
#undef STAGE_B1
#undef STAGE_B2

    // ---- epilogue: out = acc2 + b2 + h2 --------------------------------------
#pragma unroll
    for (int i = 0; i < 4; ++i)
#pragma unroll
        for (int j = 0; j < 4; ++j) {
            const int col = wn2 + j * 16 + fr;
            const float bv = b2v[col];
#pragma unroll
            for (int v = 0; v < 4; ++v) {
                const int row = m0 + i * 16 + fq * 4 + v;
                const size_t off = (size_t)row * 256 + col;
                outp[off] = acc2[i][j][v] + bv + h2[off];
            }
        }
}

// ---- MFMA window attention: one wave per (window, head) -------------------
__global__ __launch_bounds__(64, 3) void attn_kernel(
    const unsigned short* __restrict__ qkv,
    const float* __restrict__ bexp,
    unsigned short* __restrict__ out)
{
    __shared__ unsigned short VT[2048];
    const int bid  = blockIdx.x;
    const int widx = bid & 1023;
    const int head = bid >> 10;
    const int l  = threadIdx.x;
    const int lo = l & 31, hi = l >> 5;

    const unsigned short* base = qkv + (size_t)widx * 64 * 768;

#pragma unroll
    for (int c = 0; c < 4; ++c) {
        union { bf16x8 v; unsigned short s[8]; } u;
        u.v = *(const bf16x8*)(base + (size_t)l * 768 + 512 + head * 32 + c * 8);
#pragma unroll
        for (int e = 0; e < 8; ++e) {
            int d = c * 8 + e;
            int wb = ((d * 64 + l) * 2) ^ ((d & 7) << 4);
            *(unsigned short*)((char*)VT + wb) = u.s[e];
        }
    }

    f32x16 acc[2][2] = {};
#pragma unroll
    for (int kd = 0; kd < 2; ++kd) {
        const int coff = head * 32 + kd * 16 + hi * 8;
        bf16x8 kf0 = *(const bf16x8*)(base + (size_t)lo        * 768 + 256 + coff);
        bf16x8 kf1 = *(const bf16x8*)(base + (size_t)(32 + lo) * 768 + 256 + coff);
        bf16x8 qf0 = *(const bf16x8*)(base + (size_t)lo        * 768 + coff);
        bf16x8 qf1 = *(const bf16x8*)(base + (size_t)(32 + lo) * 768 + coff);
        acc[0][0] = __builtin_amdgcn_mfma_f32_32x32x16_bf16(kf0, qf0, acc[0][0], 0, 0, 0);
        acc[0][1] = __builtin_amdgcn_mfma_f32_32x32x16_bf16(kf0, qf1, acc[0][1], 0, 0, 0);
        acc[1][0] = __builtin_amdgcn_mfma_f32_32x32x16_bf16(kf1, qf0, acc[1][0], 0, 0, 0);
        acc[1][1] = __builtin_amdgcn_mfma_f32_32x32x16_bf16(kf1, qf1, acc[1][1], 0, 0, 0);
    }

#pragma unroll
    for (int qb = 0; qb < 2; ++qb) {
        const float* bq = bexp + head * 4096 + (qb * 32 + lo) * 64;
#pragma unroll
        for (int kb = 0; kb < 2; ++kb)
#pragma unroll
            for (int j = 0; j < 4; ++j) {
                float4 b4 = *(const float4*)(bq + kb * 32 + j * 8 + hi * 4);
                acc[kb][qb][4 * j + 0] += b4.x;
                acc[kb][qb][4 * j + 1] += b4.y;
                acc[kb][qb][4 * j + 2] += b4.z;
                acc[kb][qb][4 * j + 3] += b4.w;
            }
    }

    const int w6 = widx & 63;
    if (((w6 >> 3) == 7) || ((w6 & 7) == 7)) {
#pragma unroll
        for (int qb = 0; qb < 2; ++qb) {
            int nq = qb * 32 + lo;
            int phq = ((w6 >> 3) << 3) + (nq >> 3), pwq = ((w6 & 7) << 3) + (nq & 7);
            int rq = ((phq < 56) ? 0 : ((phq < 60) ? 1 : 2)) * 3
                   + ((pwq < 56) ? 0 : ((pwq < 60) ? 1 : 2));
#pragma unroll
            for (int kb = 0; kb < 2; ++kb)
#pragma unroll
                for (int r = 0; r < 16; ++r) {
                    int nk = kb * 32 + (r & 3) + 8 * (r >> 2) + 4 * hi;
                    int phk = ((w6 >> 3) << 3) + (nk >> 3), pwk = ((w6 & 7) << 3) + (nk & 7);
                    int rk = ((phk < 56) ? 0 : ((phk < 60) ? 1 : 2)) * 3
                           + ((pwk < 56) ? 0 : ((pwk < 60) ? 1 : 2));
                    if (rk != rq) acc[kb][qb][r] -= 100.0f;
                }
        }
    }

#pragma unroll
    for (int qb = 0; qb < 2; ++qb) {
        float mx = acc[0][qb][0];
#pragma unroll
        for (int r = 1; r < 16; ++r) mx = fmaxf(mx, acc[0][qb][r]);
#pragma unroll
        for (int r = 0; r < 16; ++r) mx = fmaxf(mx, acc[1][qb][r]);
        mx = fmaxf(mx, __shfl_xor(mx, 32, 64));
        float sum = 0.f;
#pragma unroll
        for (int kb = 0; kb < 2; ++kb)
#pragma unroll
            for (int r = 0; r < 16; ++r) {
                float e = __expf(acc[kb][qb][r] - mx);
                acc[kb][qb][r] = e;
                sum += e;
            }
        sum += __shfl_xor(sum, 32, 64);
        float inv = 1.0f / sum;
#pragma unroll
        for (int kb = 0; kb < 2; ++kb)
#pragma unroll
            for (int r = 0; r < 16; ++r) acc[kb][qb][r] *= inv;
    }

    f32x16 o[2] = {};
#pragma unroll
    for (int ks = 0; ks < 4; ++ks) {
        const int s8 = (ks & 1) * 8, kb = ks >> 1;
        const int rb = ((lo * 64 + 16 * ks + 8 * hi) * 2) ^ ((lo & 7) << 4);
        bf16x8 vb = *(const bf16x8*)((const char*)VT + rb);
#pragma unroll
        for (int qb = 0; qb < 2; ++qb) {
            unsigned int a0 = cvtpk_bf16(acc[kb][qb][s8 + 0], acc[kb][qb][s8 + 1]);
            unsigned int b0 = cvtpk_bf16(acc[kb][qb][s8 + 4], acc[kb][qb][s8 + 5]);
            unsigned int a1 = cvtpk_bf16(acc[kb][qb][s8 + 2], acc[kb][qb][s8 + 3]);
            unsigned int b1 = cvtpk_bf16(acc[kb][qb][s8 + 6], acc[kb][qb][s8 + 7]);
            perm32swap(a0, b0);
            perm32swap(a1, b1);
            union { unsigned int u[4]; bf16x8 v; } w;
            w.u[0] = a0; w.u[1] = a1; w.u[2] = b0; w.u[3] = b1;
            o[qb] = __builtin_amdgcn_mfma_f32_32x32x16_bf16(w.v, vb, o[qb], 0, 0, 0);
        }
    }

    unsigned short* ob = out + (size_t)widx * 64 * 256 + head * 32 + lo;
#pragma unroll
    for (int qb = 0; qb < 2; ++qb)
#pragma unroll
        for (int r = 0; r < 16; ++r) {
            int q = qb * 32 + (r & 3) + 8 * (r >> 2) + 4 * hi;
            ob[(size_t)q * 256] = f2bf(o[qb][r]);
        }
}

// ---------------------------------------------------------------------------
extern "C" void kernel_launch(void* const* d_in, const int* in_sizes, int n_in,
                              void* d_out, int out_size, void* d_ws, size_t ws_size,
                              hipStream_t stream)
{
    const float* x      = (const float*)d_in[0];
    const float* ln1_g  = (const float*)d_in[1];
    const float* ln1_b  = (const float*)d_in[2];
    const float* qkv_w  = (const float*)d_in[3];
    const float* qkv_b  = (const float*)d_in[4];
    const float* proj_w = (const float*)d_in[5];
    const float* proj_b = (const float*)d_in[6];
    const float* table  = (const float*)d_in[7];
    const float* ln2_g  = (const float*)d_in[8];
    const float* ln2_b  = (const float*)d_in[9];
    const float* w1     = (const float*)d_in[10];
    const float* b1     = (const float*)d_in[11];
    const float* w2     = (const float*)d_in[12];
    const float* b2     = (const float*)d_in[13];
    const int*   relidx = (const int*)d_in[14];
    float* out = (float*)d_out;

    char* w = (char*)d_ws;
    unsigned short* xw   = (unsigned short*)w;                      // 32MB (xw -> attn_out -> ln2out)
    unsigned short* qkvb = (unsigned short*)(w + (32u << 20));      // 96MB (qkv)
    float*          h2   = (float*)(w + (160u << 20));              // 64MB
    float*          bexp = (float*)(w + (224u << 20));              // 128KB
    unsigned short* qkvT = (unsigned short*)(w + (224u << 20) + (128u << 10)); // 384KB
    unsigned short* prjT = qkvT + 768 * 256;                        // 128KB
    unsigned short* w1T  = prjT + 256 * 256;                        // 512KB
    unsigned short* w2T  = w1T + 1024 * 256;                        // 512KB

    // 0. weight transpose + bf16 convert
    convert_T_kernel<<<192, 256, 0, stream>>>(qkv_w, qkvT, 256, 768);
    convert_T_kernel<<< 64, 256, 0, stream>>>(proj_w, prjT, 256, 256);
    convert_T_kernel<<<256, 256, 0, stream>>>(w1, w1T, 256, 1024);
    convert_T_kernel<<<256, 256, 0, stream>>>(w2, w2T, 1024, 256);
    // 1. LN1 + cyclic shift + window partition (gather) -> xw bf16 [65536,256]
    ln_kernel<<<16384, 256, 0, stream>>>(x, ln1_g, ln1_b, xw, 1);
    // 1b. expand relative-position bias to [head][q][key]
    bias_expand_kernel<<<128, 256, 0, stream>>>(table, relidx, bexp);
    // 2. QKV GEMM (q cols pre-scaled by hd^-0.5) -> qkvb bf16 [65536,768]
    mgemm_kernel<1, 0, 0, 1><<<512 * 6, 256, 0, stream>>>(xw, qkvT, qkv_b, (void*)qkvb,
                                                          nullptr, 65536, 768, 256);
    // 3. MFMA window attention -> attn_out (reuse xw) bf16 [65536,256]
    attn_kernel<<<8192, 64, 0, stream>>>(qkvb, bexp, xw);
    // 4. proj GEMM + window-reverse/unshift scatter + residual(x) -> h2 f32
    mgemm_kernel<0, 0, 2, 0><<<512 * 2, 256, 0, stream>>>(xw, prjT, proj_b, (void*)h2,
                                                          x, 65536, 256, 256);
    // 5. LN2 -> ln2out (reuse xw) bf16
    ln_kernel<<<16384, 256, 0, stream>>>(h2, ln2_g, ln2_b, xw, 0);
    // 6+7. fused MLP: out = h2 + gelu(ln2out @ w1 + b1) @ w2 + b2
    mlp_fused_kernel<<<1024, 256, 0, stream>>>(xw, w1T, b1, w2T, b2, h2, out);
}

// Round 6
// 331.405 us; speedup vs baseline: 1.1839x; 1.1839x over previous
//
#include <hip/hip_runtime.h>

// ---------------------------------------------------------------------------
// Swin block: LN1 -> shift+window -> QKV -> win-attn(+relbias+mask) -> proj
//             -> reverse+residual -> LN2 -> MLP1(GELU) -> MLP2 + residual
// B=16 H=W=64 C=256 WS=8 SHIFT=4 HEADS=8 HD=32 N=64 HID=1024
// Round 6: (a) REVERT fused MLP (R5: 1 block/CU occupancy cliff, 72 lockstep
//          barriers -> 236us). (b) all mgemm epilogues compute C^T via
//          operand-swapped MFMA: lane owns 4 consecutive N-cols -> bf16 out
//          as 16x dwordx2 (cvt_pk), f32 out as 16x dwordx4 + float4 resid
//          (was 64 scalar stores). (c) weight converts + bias expand fused
//          into one prep kernel (-4 launches).
// ---------------------------------------------------------------------------

typedef __attribute__((ext_vector_type(8))) short bf16x8;
typedef __attribute__((ext_vector_type(4))) float f32x4;
typedef __attribute__((ext_vector_type(16))) float f32x16;

__device__ __forceinline__ float bf2f(unsigned short h) {
    union { unsigned int u; float f; } c; c.u = ((unsigned int)h) << 16; return c.f;
}
__device__ __forceinline__ unsigned short f2bf(float f) {
    union { float f; unsigned int u; } c; c.f = f;
    unsigned int u = c.u;
    return (unsigned short)((u + 0x7FFFu + ((u >> 16) & 1u)) >> 16);
}
__device__ __forceinline__ unsigned int cvtpk_bf16(float lo, float hi) {
    unsigned int r;
    asm volatile("v_cvt_pk_bf16_f32 %0, %1, %2" : "=v"(r) : "v"(lo), "v"(hi));
    return r;
}
__device__ __forceinline__ void perm32swap(unsigned int& a, unsigned int& b) {
    asm volatile("v_permlane32_swap_b32 %0, %1" : "+v"(a), "+v"(b));
}
// window-order row (b, wi, wj, r, cc) -> pixel-order row (b, hp, wp).
__device__ __forceinline__ int remap_row(int row) {
    int b  = row >> 12;
    int w6 = (row >> 6) & 63;
    int n  = row & 63;
    int hp = (((w6 >> 3) << 3) + (n >> 3) + 4) & 63;
    int wp = (((w6 & 7) << 3) + (n & 7) + 4) & 63;
    return (b << 12) | (hp << 6) | wp;
}
// gelu(v) = v * sigmoid(2c(v + 0.044715 v^3)), c = sqrt(2/pi)
__device__ __forceinline__ float gelu_f(float v) {
    float u = 1.5957691216057308f * (v + 0.044715f * v * v * v);
    return v / (1.0f + __expf(-u));
}
__device__ __forceinline__ void gload16(const unsigned short* g, unsigned short* l) {
    __builtin_amdgcn_global_load_lds(
        (const __attribute__((address_space(1))) void*)g,
        (__attribute__((address_space(3))) void*)l, 16, 0, 0);
}

// ---- LayerNorm over C=256; one wave per row; optional gather remap --------
__global__ __launch_bounds__(256) void ln_kernel(
    const float* __restrict__ in, const float* __restrict__ g,
    const float* __restrict__ b, unsigned short* __restrict__ out, int remap)
{
    int wave = threadIdx.x >> 6, lane = threadIdx.x & 63;
    int row = (blockIdx.x << 2) + wave;
    int src = remap ? remap_row(row) : row;
    float4 xv = *(const float4*)(in + (size_t)src * 256 + (lane << 2));
    float s  = xv.x + xv.y + xv.z + xv.w;
    float ss = xv.x*xv.x + xv.y*xv.y + xv.z*xv.z + xv.w*xv.w;
#pragma unroll
    for (int off = 32; off; off >>= 1) {
        s  += __shfl_xor(s,  off, 64);
        ss += __shfl_xor(ss, off, 64);
    }
    float mu  = s * (1.0f / 256.0f);
    float inv = rsqrtf(ss * (1.0f / 256.0f) - mu * mu + 1e-5f);
    float4 gv = *(const float4*)(g + (lane << 2));
    float4 bv = *(const float4*)(b + (lane << 2));
    ushort4 o;
    o.x = f2bf((xv.x - mu) * inv * gv.x + bv.x);
    o.y = f2bf((xv.y - mu) * inv * gv.y + bv.y);
    o.z = f2bf((xv.z - mu) * inv * gv.z + bv.z);
    o.w = f2bf((xv.w - mu) * inv * gv.w + bv.w);
    *(ushort4*)(out + (size_t)row * 256 + (lane << 2)) = o;
}

// ---- prep: 4x weight transpose+bf16 convert, + rel-pos bias expand --------
__device__ __forceinline__ void convT_body(
    const float* __restrict__ in, unsigned short* __restrict__ out,
    int K, int N, int b, float (*t)[33], int tid)
{
    int kb = K >> 5;
    int bk = (b % kb) << 5;
    int bn = (b / kb) << 5;
    int r = tid >> 5, c = tid & 31;
#pragma unroll
    for (int i = 0; i < 4; ++i)
        t[r + i * 8][c] = in[(size_t)(bk + r + i * 8) * N + bn + c];
    __syncthreads();
#pragma unroll
    for (int i = 0; i < 4; ++i)
        out[(size_t)(bn + r + i * 8) * K + bk + c] = f2bf(t[c][r + i * 8]);
}

__global__ __launch_bounds__(256) void prep_kernel(
    const float* __restrict__ qkv_w, const float* __restrict__ proj_w,
    const float* __restrict__ w1, const float* __restrict__ w2,
    unsigned short* __restrict__ qkvT, unsigned short* __restrict__ prjT,
    unsigned short* __restrict__ w1T, unsigned short* __restrict__ w2T,
    const float* __restrict__ table, const int* __restrict__ relidx,
    float* __restrict__ bexp)
{
    __shared__ float t[32][33];
    const int b = blockIdx.x, tid = threadIdx.x;
    if      (b < 192) convT_body(qkv_w, qkvT, 256,  768, b,       t, tid);
    else if (b < 256) convT_body(proj_w, prjT, 256,  256, b - 192, t, tid);
    else if (b < 512) convT_body(w1,    w1T,  256, 1024, b - 256, t, tid);
    else if (b < 768) convT_body(w2,    w2T, 1024,  256, b - 512, t, tid);
    else {
        int i = (b - 768) * 256 + tid;       // 8*64*64 = 32768
        int head = i >> 12;
        int q = (i >> 6) & 63;
        int k = i & 63;
        bexp[i] = table[relidx[q * 64 + k] * 8 + head];
    }
}

// ---- MFMA GEMM: A bf16 [M,K] row-major, BT bf16 [N,K] row-major -----------
// 128x128 tile, BK=32, dbuf prefetch, XCD swizzle, XOR-swizzled LDS.
// Computes C^T fragments (operand-swapped MFMA): lane owns row m=fr and 4
// consecutive cols n=colbase..+3 per fragment -> vectorized epilogue.
template<int OUT_BF16, int DO_GELU, int RESID, int QSCALE>
__global__ __launch_bounds__(256) void mgemm_kernel(
    const unsigned short* __restrict__ A, const unsigned short* __restrict__ BT,
    const float* __restrict__ bias, void* __restrict__ outp,
    const float* __restrict__ resid, int M, int N, int K)
{
    __shared__ unsigned short As[2][128 * 32];
    __shared__ unsigned short Bs[2][128 * 32];

    const int cpx = (int)gridDim.x >> 3;
    const int bid = ((int)blockIdx.x & 7) * cpx + ((int)blockIdx.x >> 3);

    const int nb = N >> 7;
    const int m0 = (bid / nb) << 7;
    const int n0 = (bid % nb) << 7;
    const int tid  = threadIdx.x;
    const int wid  = tid >> 6;
    const int lane = tid & 63;
    const int wm = (wid >> 1) << 6;
    const int wn = (wid & 1) << 6;

    const unsigned short* Ag = A  + (size_t)m0 * K;
    const unsigned short* Bg = BT + (size_t)n0 * K;
    const int s0 = tid, s1 = tid + 256;
    // LDS slot s holds logical k-group (s&3)^(row&3): pre-swizzled source
    const size_t ra0 = (size_t)(s0 >> 2) * K + (((s0 & 3) ^ ((s0 >> 2) & 3)) << 3);
    const size_t ra1 = (size_t)(s1 >> 2) * K + (((s1 & 3) ^ ((s1 >> 2) & 3)) << 3);

    f32x4 acc[4][4] = {};          // acc[j][i] = C^T fragment
    const int fr = lane & 15;
    const int fq = lane >> 4;
    const int axor = ((fq ^ (fr & 3)) << 3);   // swizzled read offset (elements)

    gload16(Ag + ra0, As[0] + s0 * 8);
    gload16(Ag + ra1, As[0] + s1 * 8);
    gload16(Bg + ra0, Bs[0] + s0 * 8);
    gload16(Bg + ra1, Bs[0] + s1 * 8);
    __syncthreads();

    int cur = 0;
    for (int k0 = 0; k0 < K; k0 += 32) {
        if (k0 + 32 < K) {
            const int nxt = cur ^ 1;
            gload16(Ag + ra0 + k0 + 32, As[nxt] + s0 * 8);
            gload16(Ag + ra1 + k0 + 32, As[nxt] + s1 * 8);
            gload16(Bg + ra0 + k0 + 32, Bs[nxt] + s0 * 8);
            gload16(Bg + ra1 + k0 + 32, Bs[nxt] + s1 * 8);
        }

        bf16x8 af[4], bfr[4];
#pragma unroll
        for (int i = 0; i < 4; ++i)
            af[i] = *(const bf16x8*)(As[cur] + (wm + i * 16 + fr) * 32 + axor);
#pragma unroll
        for (int j = 0; j < 4; ++j)
            bfr[j] = *(const bf16x8*)(Bs[cur] + (wn + j * 16 + fr) * 32 + axor);
#pragma unroll
        for (int j = 0; j < 4; ++j)
#pragma unroll
            for (int i = 0; i < 4; ++i)
                acc[j][i] = __builtin_amdgcn_mfma_f32_16x16x32_bf16(
                    bfr[j], af[i], acc[j][i], 0, 0, 0);   // C^T: operands swapped
        __syncthreads();
        cur ^= 1;
    }

    // epilogue: lane -> row m0+wm+i*16+fr, cols colbase..colbase+3
#pragma unroll
    for (int j = 0; j < 4; ++j) {
        const int colbase = n0 + wn + j * 16 + (fq << 2);
        const float4 b4 = *(const float4*)(bias + colbase);
#pragma unroll
        for (int i = 0; i < 4; ++i) {
            const int row = m0 + wm + i * 16 + fr;
            float v0 = acc[j][i][0] + b4.x;
            float v1 = acc[j][i][1] + b4.y;
            float v2 = acc[j][i][2] + b4.z;
            float v3 = acc[j][i][3] + b4.w;
            if (QSCALE && colbase < 256) {   // colbase%4==0: group never straddles 256
                v0 *= 0.17677669529663687f; v1 *= 0.17677669529663687f;
                v2 *= 0.17677669529663687f; v3 *= 0.17677669529663687f;
            }
            if (DO_GELU) {
                v0 = gelu_f(v0); v1 = gelu_f(v1); v2 = gelu_f(v2); v3 = gelu_f(v3);
            }
            if (OUT_BF16) {
                uint2 pp;
                pp.x = cvtpk_bf16(v0, v1);
                pp.y = cvtpk_bf16(v2, v3);
                *(uint2*)((unsigned short*)outp + (size_t)row * N + colbase) = pp;
            } else {
                const int orow = (RESID == 2) ? remap_row(row) : row;
                float4 o4;
                if (RESID) {
                    const float4 r4 = *(const float4*)(resid + (size_t)orow * N + colbase);
                    o4.x = v0 + r4.x; o4.y = v1 + r4.y;
                    o4.z = v2 + r4.z; o4.w = v3 + r4.w;
                } else {
                    o4.x = v0; o4.y = v1; o4.z = v2; o4.w = v3;
                }
                *(float4*)((float*)outp + (size_t)orow * N + colbase) = o4;
            }
        }
    }
}

// ---- MFMA window attention: one wave per (window, head) -------------------
__global__ __launch_bounds__(64, 3) void attn_kernel(
    const unsigned short* __restrict__ qkv,
    const float* __restrict__ bexp,
    unsigned short* __restrict__ out)
{
    __shared__ unsigned short VT[2048];
    const int bid  = blockIdx.x;
    const int widx = bid & 1023;
    const int head = bid >> 10;
    const int l  = threadIdx.x;
    const int lo = l & 31, hi = l >> 5;

    const unsigned short* base = qkv + (size_t)widx * 64 * 768;

#pragma unroll
    for (int c = 0; c < 4; ++c) {
        union { bf16x8 v; unsigned short s[8]; } u;
        u.v = *(const bf16x8*)(base + (size_t)l * 768 + 512 + head * 32 + c * 8);
#pragma unroll
        for (int e = 0; e < 8; ++e) {
            int d = c * 8 + e;
            int wb = ((d * 64 + l) * 2) ^ ((d & 7) << 4);
            *(unsigned short*)((char*)VT + wb) = u.s[e];
        }
    }

    f32x16 acc[2][2] = {};
#pragma unroll
    for (int kd = 0; kd < 2; ++kd) {
        const int coff = head * 32 + kd * 16 + hi * 8;
        bf16x8 kf0 = *(const bf16x8*)(base + (size_t)lo        * 768 + 256 + coff);
        bf16x8 kf1 = *(const bf16x8*)(base + (size_t)(32 + lo) * 768 + 256 + coff);
        bf16x8 qf0 = *(const bf16x8*)(base + (size_t)lo        * 768 + coff);
        bf16x8 qf1 = *(const bf16x8*)(base + (size_t)(32 + lo) * 768 + coff);
        acc[0][0] = __builtin_amdgcn_mfma_f32_32x32x16_bf16(kf0, qf0, acc[0][0], 0, 0, 0);
        acc[0][1] = __builtin_amdgcn_mfma_f32_32x32x16_bf16(kf0, qf1, acc[0][1], 0, 0, 0);
        acc[1][0] = __builtin_amdgcn_mfma_f32_32x32x16_bf16(kf1, qf0, acc[1][0], 0, 0, 0);
        acc[1][1] = __builtin_amdgcn_mfma_f32_32x32x16_bf16(kf1, qf1, acc[1][1], 0, 0, 0);
    }

#pragma unroll
    for (int qb = 0; qb < 2; ++qb) {
        const float* bq = bexp + head * 4096 + (qb * 32 + lo) * 64;
#pragma unroll
        for (int kb = 0; kb < 2; ++kb)
#pragma unroll
            for (int j = 0; j < 4; ++j) {
                float4 b4 = *(const float4*)(bq + kb * 32 + j * 8 + hi * 4);
                acc[kb][qb][4 * j + 0] += b4.x;
                acc[kb][qb][4 * j + 1] += b4.y;
                acc[kb][qb][4 * j + 2] += b4.z;
                acc[kb][qb][4 * j + 3] += b4.w;
            }
    }

    const int w6 = widx & 63;
    if (((w6 >> 3) == 7) || ((w6 & 7) == 7)) {
#pragma unroll
        for (int qb = 0; qb < 2; ++qb) {
            int nq = qb * 32 + lo;
            int phq = ((w6 >> 3) << 3) + (nq >> 3), pwq = ((w6 & 7) << 3) + (nq & 7);
            int rq = ((phq < 56) ? 0 : ((phq < 60) ? 1 : 2)) * 3
                   + ((pwq < 56) ? 0 : ((pwq < 60) ? 1 : 2));
#pragma unroll
            for (int kb = 0; kb < 2; ++kb)
#pragma unroll
                for (int r = 0; r < 16; ++r) {
                    int nk = kb * 32 + (r & 3) + 8 * (r >> 2) + 4 * hi;
                    int phk = ((w6 >> 3) << 3) + (nk >> 3), pwk = ((w6 & 7) << 3) + (nk & 7);
                    int rk = ((phk < 56) ? 0 : ((phk < 60) ? 1 : 2)) * 3
                           + ((pwk < 56) ? 0 : ((pwk < 60) ? 1 : 2));
                    if (rk != rq) acc[kb][qb][r] -= 100.0f;
                }
        }
    }

#pragma unroll
    for (int qb = 0; qb < 2; ++qb) {
        float mx = acc[0][qb][0];
#pragma unroll
        for (int r = 1; r < 16; ++r) mx = fmaxf(mx, acc[0][qb][r]);
#pragma unroll
        for (int r = 0; r < 16; ++r) mx = fmaxf(mx, acc[1][qb][r]);
        mx = fmaxf(mx, __shfl_xor(mx, 32, 64));
        float sum = 0.f;
#pragma unroll
        for (int kb = 0; kb < 2; ++kb)
#pragma unroll
            for (int r = 0; r < 16; ++r) {
                float e = __expf(acc[kb][qb][r] - mx);
                acc[kb][qb][r] = e;
                sum += e;
            }
        sum += __shfl_xor(sum, 32, 64);
        float inv = 1.0f / sum;
#pragma unroll
        for (int kb = 0; kb < 2; ++kb)
#pragma unroll
            for (int r = 0; r < 16; ++r) acc[kb][qb][r] *= inv;
    }

    f32x16 o[2] = {};
#pragma unroll
    for (int ks = 0; ks < 4; ++ks) {
        const int s8 = (ks & 1) * 8, kb = ks >> 1;
        const int rb = ((lo * 64 + 16 * ks + 8 * hi) * 2) ^ ((lo & 7) << 4);
        bf16x8 vb = *(const bf16x8*)((const char*)VT + rb);
#pragma unroll
        for (int qb = 0; qb < 2; ++qb) {
            unsigned int a0 = cvtpk_bf16(acc[kb][qb][s8 + 0], acc[kb][qb][s8 + 1]);
            unsigned int b0 = cvtpk_bf16(acc[kb][qb][s8 + 4], acc[kb][qb][s8 + 5]);
            unsigned int a1 = cvtpk_bf16(acc[kb][qb][s8 + 2], acc[kb][qb][s8 + 3]);
            unsigned int b1 = cvtpk_bf16(acc[kb][qb][s8 + 6], acc[kb][qb][s8 + 7]);
            perm32swap(a0, b0);
            perm32swap(a1, b1);
            union { unsigned int u[4]; bf16x8 v; } w;
            w.u[0] = a0; w.u[1] = a1; w.u[2] = b0; w.u[3] = b1;
            o[qb] = __builtin_amdgcn_mfma_f32_32x32x16_bf16(w.v, vb, o[qb], 0, 0, 0);
        }
    }

    unsigned short* ob = out + (size_t)widx * 64 * 256 + head * 32 + lo;
#pragma unroll
    for (int qb = 0; qb < 2; ++qb)
#pragma unroll
        for (int r = 0; r < 16; ++r) {
            int q = qb * 32 + (r & 3) + 8 * (r >> 2) + 4 * hi;
            ob[(size_t)q * 256] = f2bf(o[qb][r]);
        }
}

// ---------------------------------------------------------------------------
extern "C" void kernel_launch(void* const* d_in, const int* in_sizes, int n_in,
                              void* d_out, int out_size, void* d_ws, size_t ws_size,
                              hipStream_t stream)
{
    const float* x      = (const float*)d_in[0];
    const float* ln1_g  = (const float*)d_in[1];
    const float* ln1_b  = (const float*)d_in[2];
    const float* qkv_w  = (const float*)d_in[3];
    const float* qkv_b  = (const float*)d_in[4];
    const float* proj_w = (const float*)d_in[5];
    const float* proj_b = (const float*)d_in[6];
    const float* table  = (const float*)d_in[7];
    const float* ln2_g  = (const float*)d_in[8];
    const float* ln2_b  = (const float*)d_in[9];
    const float* w1     = (const float*)d_in[10];
    const float* b1     = (const float*)d_in[11];
    const float* w2     = (const float*)d_in[12];
    const float* b2     = (const float*)d_in[13];
    const int*   relidx = (const int*)d_in[14];
    float* out = (float*)d_out;

    char* w = (char*)d_ws;
    unsigned short* xw   = (unsigned short*)w;                      // 32MB (xw -> attn_out -> ln2out)
    unsigned short* qkvb = (unsigned short*)(w + (32u << 20));      // 128MB (qkv 96MB -> mlp hidden 128MB)
    float*          h2   = (float*)(w + (160u << 20));              // 64MB
    float*          bexp = (float*)(w + (224u << 20));              // 128KB
    unsigned short* qkvT = (unsigned short*)(w + (224u << 20) + (128u << 10)); // 384KB
    unsigned short* prjT = qkvT + 768 * 256;                        // 128KB
    unsigned short* w1T  = prjT + 256 * 256;                        // 512KB
    unsigned short* w2T  = w1T + 1024 * 256;                        // 512KB

    // 0. weight transposes + bf16 convert + rel-pos bias expand (one kernel)
    prep_kernel<<<896, 256, 0, stream>>>(qkv_w, proj_w, w1, w2,
                                         qkvT, prjT, w1T, w2T,
                                         table, relidx, bexp);
    // 1. LN1 + cyclic shift + window partition (gather) -> xw bf16 [65536,256]
    ln_kernel<<<16384, 256, 0, stream>>>(x, ln1_g, ln1_b, xw, 1);
    // 2. QKV GEMM (q cols pre-scaled by hd^-0.5) -> qkvb bf16 [65536,768]
    mgemm_kernel<1, 0, 0, 1><<<512 * 6, 256, 0, stream>>>(xw, qkvT, qkv_b, (void*)qkvb,
                                                          nullptr, 65536, 768, 256);
    // 3. MFMA window attention -> attn_out (reuse xw) bf16 [65536,256]
    attn_kernel<<<8192, 64, 0, stream>>>(qkvb, bexp, xw);
    // 4. proj GEMM + window-reverse/unshift scatter + residual(x) -> h2 f32
    mgemm_kernel<0, 0, 2, 0><<<512 * 2, 256, 0, stream>>>(xw, prjT, proj_b, (void*)h2,
                                                          x, 65536, 256, 256);
    // 5. LN2 -> ln2out (reuse xw) bf16
    ln_kernel<<<16384, 256, 0, stream>>>(h2, ln2_g, ln2_b, xw, 0);
    // 6. MLP1 GEMM + GELU -> hidden (reuse qkvb) bf16 [65536,1024]
    mgemm_kernel<1, 1, 0, 0><<<512 * 8, 256, 0, stream>>>(xw, w1T, b1, (void*)qkvb,
                                                          nullptr, 65536, 1024, 256);
    // 7. MLP2 GEMM + residual(h2) -> d_out f32
    mgemm_kernel<0, 0, 1, 0><<<512 * 2, 256, 0, stream>>>(qkvb, w2T, b2, (void*)out,
                                                          h2, 65536, 256, 1024);
}

// Round 7
// 326.256 us; speedup vs baseline: 1.2026x; 1.0158x over previous
//
#include <hip/hip_runtime.h>

// ---------------------------------------------------------------------------
// Swin block: LN1 -> shift+window -> QKV -> win-attn(+relbias+mask) -> proj
//             -> reverse+residual -> LN2 -> MLP1(GELU) -> MLP2 + residual
// B=16 H=W=64 C=256 WS=8 SHIFT=4 HEADS=8 HD=32 N=64 HID=1024
// Round 7: counted-vmcnt double-buffer K-loop (T4) in mgemm: raw s_barrier +
//          s_waitcnt vmcnt(4) (never 0 mid-loop) so staged loads stay in
//          flight across barriers. R6 analysis: real regs = 84 VGPR + 64 AGPR
//          -> ~1 block/CU resident; compiler's vmcnt(0)-drain at each
//          __syncthreads serialized HBM latency per K-iter.
// ---------------------------------------------------------------------------

typedef __attribute__((ext_vector_type(8))) short bf16x8;
typedef __attribute__((ext_vector_type(4))) float f32x4;
typedef __attribute__((ext_vector_type(16))) float f32x16;

__device__ __forceinline__ float bf2f(unsigned short h) {
    union { unsigned int u; float f; } c; c.u = ((unsigned int)h) << 16; return c.f;
}
__device__ __forceinline__ unsigned short f2bf(float f) {
    union { float f; unsigned int u; } c; c.f = f;
    unsigned int u = c.u;
    return (unsigned short)((u + 0x7FFFu + ((u >> 16) & 1u)) >> 16);
}
__device__ __forceinline__ unsigned int cvtpk_bf16(float lo, float hi) {
    unsigned int r;
    asm volatile("v_cvt_pk_bf16_f32 %0, %1, %2" : "=v"(r) : "v"(lo), "v"(hi));
    return r;
}
__device__ __forceinline__ void perm32swap(unsigned int& a, unsigned int& b) {
    asm volatile("v_permlane32_swap_b32 %0, %1" : "+v"(a), "+v"(b));
}
// window-order row (b, wi, wj, r, cc) -> pixel-order row (b, hp, wp).
__device__ __forceinline__ int remap_row(int row) {
    int b  = row >> 12;
    int w6 = (row >> 6) & 63;
    int n  = row & 63;
    int hp = (((w6 >> 3) << 3) + (n >> 3) + 4) & 63;
    int wp = (((w6 & 7) << 3) + (n & 7) + 4) & 63;
    return (b << 12) | (hp << 6) | wp;
}
// gelu(v) = v * sigmoid(2c(v + 0.044715 v^3)), c = sqrt(2/pi)
__device__ __forceinline__ float gelu_f(float v) {
    float u = 1.5957691216057308f * (v + 0.044715f * v * v * v);
    return v / (1.0f + __expf(-u));
}
__device__ __forceinline__ void gload16(const unsigned short* g, unsigned short* l) {
    __builtin_amdgcn_global_load_lds(
        (const __attribute__((address_space(1))) void*)g,
        (__attribute__((address_space(3))) void*)l, 16, 0, 0);
}

// ---- LayerNorm over C=256; one wave per row; optional gather remap --------
__global__ __launch_bounds__(256) void ln_kernel(
    const float* __restrict__ in, const float* __restrict__ g,
    const float* __restrict__ b, unsigned short* __restrict__ out, int remap)
{
    int wave = threadIdx.x >> 6, lane = threadIdx.x & 63;
    int row = (blockIdx.x << 2) + wave;
    int src = remap ? remap_row(row) : row;
    float4 xv = *(const float4*)(in + (size_t)src * 256 + (lane << 2));
    float s  = xv.x + xv.y + xv.z + xv.w;
    float ss = xv.x*xv.x + xv.y*xv.y + xv.z*xv.z + xv.w*xv.w;
#pragma unroll
    for (int off = 32; off; off >>= 1) {
        s  += __shfl_xor(s,  off, 64);
        ss += __shfl_xor(ss, off, 64);
    }
    float mu  = s * (1.0f / 256.0f);
    float inv = rsqrtf(ss * (1.0f / 256.0f) - mu * mu + 1e-5f);
    float4 gv = *(const float4*)(g + (lane << 2));
    float4 bv = *(const float4*)(b + (lane << 2));
    ushort4 o;
    o.x = f2bf((xv.x - mu) * inv * gv.x + bv.x);
    o.y = f2bf((xv.y - mu) * inv * gv.y + bv.y);
    o.z = f2bf((xv.z - mu) * inv * gv.z + bv.z);
    o.w = f2bf((xv.w - mu) * inv * gv.w + bv.w);
    *(ushort4*)(out + (size_t)row * 256 + (lane << 2)) = o;
}

// ---- prep: 4x weight transpose+bf16 convert, + rel-pos bias expand --------
__device__ __forceinline__ void convT_body(
    const float* __restrict__ in, unsigned short* __restrict__ out,
    int K, int N, int b, float (*t)[33], int tid)
{
    int kb = K >> 5;
    int bk = (b % kb) << 5;
    int bn = (b / kb) << 5;
    int r = tid >> 5, c = tid & 31;
#pragma unroll
    for (int i = 0; i < 4; ++i)
        t[r + i * 8][c] = in[(size_t)(bk + r + i * 8) * N + bn + c];
    __syncthreads();
#pragma unroll
    for (int i = 0; i < 4; ++i)
        out[(size_t)(bn + r + i * 8) * K + bk + c] = f2bf(t[c][r + i * 8]);
}

__global__ __launch_bounds__(256) void prep_kernel(
    const float* __restrict__ qkv_w, const float* __restrict__ proj_w,
    const float* __restrict__ w1, const float* __restrict__ w2,
    unsigned short* __restrict__ qkvT, unsigned short* __restrict__ prjT,
    unsigned short* __restrict__ w1T, unsigned short* __restrict__ w2T,
    const float* __restrict__ table, const int* __restrict__ relidx,
    float* __restrict__ bexp)
{
    __shared__ float t[32][33];
    const int b = blockIdx.x, tid = threadIdx.x;
    if      (b < 192) convT_body(qkv_w, qkvT, 256,  768, b,       t, tid);
    else if (b < 256) convT_body(proj_w, prjT, 256,  256, b - 192, t, tid);
    else if (b < 512) convT_body(w1,    w1T,  256, 1024, b - 256, t, tid);
    else if (b < 768) convT_body(w2,    w2T, 1024,  256, b - 512, t, tid);
    else {
        int i = (b - 768) * 256 + tid;       // 8*64*64 = 32768
        int head = i >> 12;
        int q = (i >> 6) & 63;
        int k = i & 63;
        bexp[i] = table[relidx[q * 64 + k] * 8 + head];
    }
}

// ---- MFMA GEMM: A bf16 [M,K] row-major, BT bf16 [N,K] row-major -----------
// 128x128 tile, BK=32, counted-vmcnt dbuf (T4), XCD swizzle, XOR-swizzled LDS.
// C^T fragments (operand-swapped MFMA): lane owns 4 consecutive N-cols.
template<int OUT_BF16, int DO_GELU, int RESID, int QSCALE>
__global__ __launch_bounds__(256) void mgemm_kernel(
    const unsigned short* __restrict__ A, const unsigned short* __restrict__ BT,
    const float* __restrict__ bias, void* __restrict__ outp,
    const float* __restrict__ resid, int M, int N, int K)
{
    __shared__ unsigned short As[2][128 * 32];
    __shared__ unsigned short Bs[2][128 * 32];

    const int cpx = (int)gridDim.x >> 3;
    const int bid = ((int)blockIdx.x & 7) * cpx + ((int)blockIdx.x >> 3);

    const int nb = N >> 7;
    const int m0 = (bid / nb) << 7;
    const int n0 = (bid % nb) << 7;
    const int tid  = threadIdx.x;
    const int wid  = tid >> 6;
    const int lane = tid & 63;
    const int wm = (wid >> 1) << 6;
    const int wn = (wid & 1) << 6;

    const unsigned short* Ag = A  + (size_t)m0 * K;
    const unsigned short* Bg = BT + (size_t)n0 * K;
    const int s0 = tid, s1 = tid + 256;
    // LDS slot s holds logical k-group (s&3)^(row&3): pre-swizzled source
    const size_t ra0 = (size_t)(s0 >> 2) * K + (((s0 & 3) ^ ((s0 >> 2) & 3)) << 3);
    const size_t ra1 = (size_t)(s1 >> 2) * K + (((s1 & 3) ^ ((s1 >> 2) & 3)) << 3);

    f32x4 acc[4][4] = {};          // acc[j][i] = C^T fragment
    const int fr = lane & 15;
    const int fq = lane >> 4;
    const int axor = ((fq ^ (fr & 3)) << 3);   // swizzled read offset (elements)

    // uniform per-wave staging: 4 gload16 per thread per buffer fill
#define STAGE(buf, kk)                                                        \
    {                                                                         \
        gload16(Ag + ra0 + (kk), As[buf] + s0 * 8);                           \
        gload16(Ag + ra1 + (kk), As[buf] + s1 * 8);                           \
        gload16(Bg + ra0 + (kk), Bs[buf] + s0 * 8);                           \
        gload16(Bg + ra1 + (kk), Bs[buf] + s1 * 8);                           \
    }

    // prologue: fill both buffers, wait only for buf0 (4 newest stay in flight)
    STAGE(0, 0);
    STAGE(1, 32);
    asm volatile("s_waitcnt vmcnt(4)" ::: "memory");
    __builtin_amdgcn_s_barrier();
    __builtin_amdgcn_sched_barrier(0);

    for (int k0 = 0; k0 < K; k0 += 32) {
        const int cur = (k0 >> 5) & 1;
        bf16x8 af[4], bfr[4];
#pragma unroll
        for (int i = 0; i < 4; ++i)
            af[i] = *(const bf16x8*)(As[cur] + (wm + i * 16 + fr) * 32 + axor);
#pragma unroll
        for (int j = 0; j < 4; ++j)
            bfr[j] = *(const bf16x8*)(Bs[cur] + (wn + j * 16 + fr) * 32 + axor);
#pragma unroll
        for (int j = 0; j < 4; ++j)
#pragma unroll
            for (int i = 0; i < 4; ++i)
                acc[j][i] = __builtin_amdgcn_mfma_f32_16x16x32_bf16(
                    bfr[j], af[i], acc[j][i], 0, 0, 0);   // C^T: operands swapped

        if (k0 + 32 < K) {
            // all waves done reading buf[cur] (frag regs loaded before MFMA issue)
            __builtin_amdgcn_s_barrier();
            if (k0 + 64 < K) {
                STAGE(cur, k0 + 64);   // refill the buffer just consumed
                asm volatile("s_waitcnt vmcnt(4)" ::: "memory"); // next buf landed
            } else {
                asm volatile("s_waitcnt vmcnt(0)" ::: "memory"); // last buf landed
            }
            __builtin_amdgcn_s_barrier();
            __builtin_amdgcn_sched_barrier(0);
        }
    }
#undef STAGE

    // epilogue: lane -> row m0+wm+i*16+fr, cols colbase..colbase+3
#pragma unroll
    for (int j = 0; j < 4; ++j) {
        const int colbase = n0 + wn + j * 16 + (fq << 2);
        const float4 b4 = *(const float4*)(bias + colbase);
#pragma unroll
        for (int i = 0; i < 4; ++i) {
            const int row = m0 + wm + i * 16 + fr;
            float v0 = acc[j][i][0] + b4.x;
            float v1 = acc[j][i][1] + b4.y;
            float v2 = acc[j][i][2] + b4.z;
            float v3 = acc[j][i][3] + b4.w;
            if (QSCALE && colbase < 256) {   // colbase%4==0: group never straddles 256
                v0 *= 0.17677669529663687f; v1 *= 0.17677669529663687f;
                v2 *= 0.17677669529663687f; v3 *= 0.17677669529663687f;
            }
            if (DO_GELU) {
                v0 = gelu_f(v0); v1 = gelu_f(v1); v2 = gelu_f(v2); v3 = gelu_f(v3);
            }
            if (OUT_BF16) {
                uint2 pp;
                pp.x = cvtpk_bf16(v0, v1);
                pp.y = cvtpk_bf16(v2, v3);
                *(uint2*)((unsigned short*)outp + (size_t)row * N + colbase) = pp;
            } else {
                const int orow = (RESID == 2) ? remap_row(row) : row;
                float4 o4;
                if (RESID) {
                    const float4 r4 = *(const float4*)(resid + (size_t)orow * N + colbase);
                    o4.x = v0 + r4.x; o4.y = v1 + r4.y;
                    o4.z = v2 + r4.z; o4.w = v3 + r4.w;
                } else {
                    o4.x = v0; o4.y = v1; o4.z = v2; o4.w = v3;
                }
                *(float4*)((float*)outp + (size_t)orow * N + colbase) = o4;
            }
        }
    }
}

// ---- MFMA window attention: one wave per (window, head) -------------------
__global__ __launch_bounds__(64, 3) void attn_kernel(
    const unsigned short* __restrict__ qkv,
    const float* __restrict__ bexp,
    unsigned short* __restrict__ out)
{
    __shared__ unsigned short VT[2048];
    const int bid  = blockIdx.x;
    const int widx = bid & 1023;
    const int head = bid >> 10;
    const int l  = threadIdx.x;
    const int lo = l & 31, hi = l >> 5;

    const unsigned short* base = qkv + (size_t)widx * 64 * 768;

#pragma unroll
    for (int c = 0; c < 4; ++c) {
        union { bf16x8 v; unsigned short s[8]; } u;
        u.v = *(const bf16x8*)(base + (size_t)l * 768 + 512 + head * 32 + c * 8);
#pragma unroll
        for (int e = 0; e < 8; ++e) {
            int d = c * 8 + e;
            int wb = ((d * 64 + l) * 2) ^ ((d & 7) << 4);
            *(unsigned short*)((char*)VT + wb) = u.s[e];
        }
    }

    f32x16 acc[2][2] = {};
#pragma unroll
    for (int kd = 0; kd < 2; ++kd) {
        const int coff = head * 32 + kd * 16 + hi * 8;
        bf16x8 kf0 = *(const bf16x8*)(base + (size_t)lo        * 768 + 256 + coff);
        bf16x8 kf1 = *(const bf16x8*)(base + (size_t)(32 + lo) * 768 + 256 + coff);
        bf16x8 qf0 = *(const bf16x8*)(base + (size_t)lo        * 768 + coff);
        bf16x8 qf1 = *(const bf16x8*)(base + (size_t)(32 + lo) * 768 + coff);
        acc[0][0] = __builtin_amdgcn_mfma_f32_32x32x16_bf16(kf0, qf0, acc[0][0], 0, 0, 0);
        acc[0][1] = __builtin_amdgcn_mfma_f32_32x32x16_bf16(kf0, qf1, acc[0][1], 0, 0, 0);
        acc[1][0] = __builtin_amdgcn_mfma_f32_32x32x16_bf16(kf1, qf0, acc[1][0], 0, 0, 0);
        acc[1][1] = __builtin_amdgcn_mfma_f32_32x32x16_bf16(kf1, qf1, acc[1][1], 0, 0, 0);
    }

#pragma unroll
    for (int qb = 0; qb < 2; ++qb) {
        const float* bq = bexp + head * 4096 + (qb * 32 + lo) * 64;
#pragma unroll
        for (int kb = 0; kb < 2; ++kb)
#pragma unroll
            for (int j = 0; j < 4; ++j) {
                float4 b4 = *(const float4*)(bq + kb * 32 + j * 8 + hi * 4);
                acc[kb][qb][4 * j + 0] += b4.x;
                acc[kb][qb][4 * j + 1] += b4.y;
                acc[kb][qb][4 * j + 2] += b4.z;
                acc[kb][qb][4 * j + 3] += b4.w;
            }
    }

    const int w6 = widx & 63;
    if (((w6 >> 3) == 7) || ((w6 & 7) == 7)) {
#pragma unroll
        for (int qb = 0; qb < 2; ++qb) {
            int nq = qb * 32 + lo;
            int phq = ((w6 >> 3) << 3) + (nq >> 3), pwq = ((w6 & 7) << 3) + (nq & 7);
            int rq = ((phq < 56) ? 0 : ((phq < 60) ? 1 : 2)) * 3
                   + ((pwq < 56) ? 0 : ((pwq < 60) ? 1 : 2));
#pragma unroll
            for (int kb = 0; kb < 2; ++kb)
#pragma unroll
                for (int r = 0; r < 16; ++r) {
                    int nk = kb * 32 + (r & 3) + 8 * (r >> 2) + 4 * hi;
                    int phk = ((w6 >> 3) << 3) + (nk >> 3), pwk = ((w6 & 7) << 3) + (nk & 7);
                    int rk = ((phk < 56) ? 0 : ((phk < 60) ? 1 : 2)) * 3
                           + ((pwk < 56) ? 0 : ((pwk < 60) ? 1 : 2));
                    if (rk != rq) acc[kb][qb][r] -= 100.0f;
                }
        }
    }

#pragma unroll
    for (int qb = 0; qb < 2; ++qb) {
        float mx = acc[0][qb][0];
#pragma unroll
        for (int r = 1; r < 16; ++r) mx = fmaxf(mx, acc[0][qb][r]);
#pragma unroll
        for (int r = 0; r < 16; ++r) mx = fmaxf(mx, acc[1][qb][r]);
        mx = fmaxf(mx, __shfl_xor(mx, 32, 64));
        float sum = 0.f;
#pragma unroll
        for (int kb = 0; kb < 2; ++kb)
#pragma unroll
            for (int r = 0; r < 16; ++r) {
                float e = __expf(acc[kb][qb][r] - mx);
                acc[kb][qb][r] = e;
                sum += e;
            }
        sum += __shfl_xor(sum, 32, 64);
        float inv = 1.0f / sum;
#pragma unroll
        for (int kb = 0; kb < 2; ++kb)
#pragma unroll
            for (int r = 0; r < 16; ++r) acc[kb][qb][r] *= inv;
    }

    f32x16 o[2] = {};
#pragma unroll
    for (int ks = 0; ks < 4; ++ks) {
        const int s8 = (ks & 1) * 8, kb = ks >> 1;
        const int rb = ((lo * 64 + 16 * ks + 8 * hi) * 2) ^ ((lo & 7) << 4);
        bf16x8 vb = *(const bf16x8*)((const char*)VT + rb);
#pragma unroll
        for (int qb = 0; qb < 2; ++qb) {
            unsigned int a0 = cvtpk_bf16(acc[kb][qb][s8 + 0], acc[kb][qb][s8 + 1]);
            unsigned int b0 = cvtpk_bf16(acc[kb][qb][s8 + 4], acc[kb][qb][s8 + 5]);
            unsigned int a1 = cvtpk_bf16(acc[kb][qb][s8 + 2], acc[kb][qb][s8 + 3]);
            unsigned int b1 = cvtpk_bf16(acc[kb][qb][s8 + 6], acc[kb][qb][s8 + 7]);
            perm32swap(a0, b0);
            perm32swap(a1, b1);
            union { unsigned int u[4]; bf16x8 v; } w;
            w.u[0] = a0; w.u[1] = a1; w.u[2] = b0; w.u[3] = b1;
            o[qb] = __builtin_amdgcn_mfma_f32_32x32x16_bf16(w.v, vb, o[qb], 0, 0, 0);
        }
    }

    unsigned short* ob = out + (size_t)widx * 64 * 256 + head * 32 + lo;
#pragma unroll
    for (int qb = 0; qb < 2; ++qb)
#pragma unroll
        for (int r = 0; r < 16; ++r) {
            int q = qb * 32 + (r & 3) + 8 * (r >> 2) + 4 * hi;
            ob[(size_t)q * 256] = f2bf(o[qb][r]);
        }
}

// ---------------------------------------------------------------------------
extern "C" void kernel_launch(void* const* d_in, const int* in_sizes, int n_in,
                              void* d_out, int out_size, void* d_ws, size_t ws_size,
                              hipStream_t stream)
{
    const float* x      = (const float*)d_in[0];
    const float* ln1_g  = (const float*)d_in[1];
    const float* ln1_b  = (const float*)d_in[2];
    const float* qkv_w  = (const float*)d_in[3];
    const float* qkv_b  = (const float*)d_in[4];
    const float* proj_w = (const float*)d_in[5];
    const float* proj_b = (const float*)d_in[6];
    const float* table  = (const float*)d_in[7];
    const float* ln2_g  = (const float*)d_in[8];
    const float* ln2_b  = (const float*)d_in[9];
    const float* w1     = (const float*)d_in[10];
    const float* b1     = (const float*)d_in[11];
    const float* w2     = (const float*)d_in[12];
    const float* b2     = (const float*)d_in[13];
    const int*   relidx = (const int*)d_in[14];
    float* out = (float*)d_out;

    char* w = (char*)d_ws;
    unsigned short* xw   = (unsigned short*)w;                      // 32MB (xw -> attn_out -> ln2out)
    unsigned short* qkvb = (unsigned short*)(w + (32u << 20));      // 128MB (qkv 96MB -> mlp hidden 128MB)
    float*          h2   = (float*)(w + (160u << 20));              // 64MB
    float*          bexp = (float*)(w + (224u << 20));              // 128KB
    unsigned short* qkvT = (unsigned short*)(w + (224u << 20) + (128u << 10)); // 384KB
    unsigned short* prjT = qkvT + 768 * 256;                        // 128KB
    unsigned short* w1T  = prjT + 256 * 256;                        // 512KB
    unsigned short* w2T  = w1T + 1024 * 256;                        // 512KB

    // 0. weight transposes + bf16 convert + rel-pos bias expand (one kernel)
    prep_kernel<<<896, 256, 0, stream>>>(qkv_w, proj_w, w1, w2,
                                         qkvT, prjT, w1T, w2T,
                                         table, relidx, bexp);
    // 1. LN1 + cyclic shift + window partition (gather) -> xw bf16 [65536,256]
    ln_kernel<<<16384, 256, 0, stream>>>(x, ln1_g, ln1_b, xw, 1);
    // 2. QKV GEMM (q cols pre-scaled by hd^-0.5) -> qkvb bf16 [65536,768]
    mgemm_kernel<1, 0, 0, 1><<<512 * 6, 256, 0, stream>>>(xw, qkvT, qkv_b, (void*)qkvb,
                                                          nullptr, 65536, 768, 256);
    // 3. MFMA window attention -> attn_out (reuse xw) bf16 [65536,256]
    attn_kernel<<<8192, 64, 0, stream>>>(qkvb, bexp, xw);
    // 4. proj GEMM + window-reverse/unshift scatter + residual(x) -> h2 f32
    mgemm_kernel<0, 0, 2, 0><<<512 * 2, 256, 0, stream>>>(xw, prjT, proj_b, (void*)h2,
                                                          x, 65536, 256, 256);
    // 5. LN2 -> ln2out (reuse xw) bf16
    ln_kernel<<<16384, 256, 0, stream>>>(h2, ln2_g, ln2_b, xw, 0);
    // 6. MLP1 GEMM + GELU -> hidden (reuse qkvb) bf16 [65536,1024]
    mgemm_kernel<1, 1, 0, 0><<<512 * 8, 256, 0, stream>>>(xw, w1T, b1, (void*)qkvb,
                                                          nullptr, 65536, 1024, 256);
    // 7. MLP2 GEMM + residual(h2) -> d_out f32
    mgemm_kernel<0, 0, 1, 0><<<512 * 2, 256, 0, stream>>>(qkvb, w2T, b2, (void*)out,
                                                          h2, 65536, 256, 1024);
}

// Round 8
// 311.042 us; speedup vs baseline: 1.2614x; 1.0489x over previous
//
#include <hip/hip_runtime.h>

// ---------------------------------------------------------------------------
// Swin block: LN1 -> shift+window -> QKV -> win-attn(+relbias+mask) -> proj
//             -> reverse+residual -> LN2 -> MLP1(GELU) -> MLP2 + residual
// B=16 H=W=64 C=256 WS=8 SHIFT=4 HEADS=8 HD=32 N=64 HID=1024
// Round 8: mgemm -> 512 threads / 8 waves per 128x128 tile (wave = 32x64,
//          acc 32 AGPR, ~100 regs) with __launch_bounds__(512,4):
//          16 waves/CU from 2 independent blocks. R7 diagnosis: GEMMs are
//          latency-bound at 12 waves/CU lockstep; occupancy is the lever.
// ---------------------------------------------------------------------------

typedef __attribute__((ext_vector_type(8))) short bf16x8;
typedef __attribute__((ext_vector_type(4))) float f32x4;
typedef __attribute__((ext_vector_type(16))) float f32x16;

__device__ __forceinline__ float bf2f(unsigned short h) {
    union { unsigned int u; float f; } c; c.u = ((unsigned int)h) << 16; return c.f;
}
__device__ __forceinline__ unsigned short f2bf(float f) {
    union { float f; unsigned int u; } c; c.f = f;
    unsigned int u = c.u;
    return (unsigned short)((u + 0x7FFFu + ((u >> 16) & 1u)) >> 16);
}
__device__ __forceinline__ unsigned int cvtpk_bf16(float lo, float hi) {
    unsigned int r;
    asm volatile("v_cvt_pk_bf16_f32 %0, %1, %2" : "=v"(r) : "v"(lo), "v"(hi));
    return r;
}
__device__ __forceinline__ void perm32swap(unsigned int& a, unsigned int& b) {
    asm volatile("v_permlane32_swap_b32 %0, %1" : "+v"(a), "+v"(b));
}
// window-order row (b, wi, wj, r, cc) -> pixel-order row (b, hp, wp).
__device__ __forceinline__ int remap_row(int row) {
    int b  = row >> 12;
    int w6 = (row >> 6) & 63;
    int n  = row & 63;
    int hp = (((w6 >> 3) << 3) + (n >> 3) + 4) & 63;
    int wp = (((w6 & 7) << 3) + (n & 7) + 4) & 63;
    return (b << 12) | (hp << 6) | wp;
}
// gelu(v) = v * sigmoid(2c(v + 0.044715 v^3)), c = sqrt(2/pi)
__device__ __forceinline__ float gelu_f(float v) {
    float u = 1.5957691216057308f * (v + 0.044715f * v * v * v);
    return v / (1.0f + __expf(-u));
}
__device__ __forceinline__ void gload16(const unsigned short* g, unsigned short* l) {
    __builtin_amdgcn_global_load_lds(
        (const __attribute__((address_space(1))) void*)g,
        (__attribute__((address_space(3))) void*)l, 16, 0, 0);
}

// ---- LayerNorm over C=256; one wave per row; optional gather remap --------
__global__ __launch_bounds__(256) void ln_kernel(
    const float* __restrict__ in, const float* __restrict__ g,
    const float* __restrict__ b, unsigned short* __restrict__ out, int remap)
{
    int wave = threadIdx.x >> 6, lane = threadIdx.x & 63;
    int row = (blockIdx.x << 2) + wave;
    int src = remap ? remap_row(row) : row;
    float4 xv = *(const float4*)(in + (size_t)src * 256 + (lane << 2));
    float s  = xv.x + xv.y + xv.z + xv.w;
    float ss = xv.x*xv.x + xv.y*xv.y + xv.z*xv.z + xv.w*xv.w;
#pragma unroll
    for (int off = 32; off; off >>= 1) {
        s  += __shfl_xor(s,  off, 64);
        ss += __shfl_xor(ss, off, 64);
    }
    float mu  = s * (1.0f / 256.0f);
    float inv = rsqrtf(ss * (1.0f / 256.0f) - mu * mu + 1e-5f);
    float4 gv = *(const float4*)(g + (lane << 2));
    float4 bv = *(const float4*)(b + (lane << 2));
    ushort4 o;
    o.x = f2bf((xv.x - mu) * inv * gv.x + bv.x);
    o.y = f2bf((xv.y - mu) * inv * gv.y + bv.y);
    o.z = f2bf((xv.z - mu) * inv * gv.z + bv.z);
    o.w = f2bf((xv.w - mu) * inv * gv.w + bv.w);
    *(ushort4*)(out + (size_t)row * 256 + (lane << 2)) = o;
}

// ---- prep: 4x weight transpose+bf16 convert, + rel-pos bias expand --------
__device__ __forceinline__ void convT_body(
    const float* __restrict__ in, unsigned short* __restrict__ out,
    int K, int N, int b, float (*t)[33], int tid)
{
    int kb = K >> 5;
    int bk = (b % kb) << 5;
    int bn = (b / kb) << 5;
    int r = tid >> 5, c = tid & 31;
#pragma unroll
    for (int i = 0; i < 4; ++i)
        t[r + i * 8][c] = in[(size_t)(bk + r + i * 8) * N + bn + c];
    __syncthreads();
#pragma unroll
    for (int i = 0; i < 4; ++i)
        out[(size_t)(bn + r + i * 8) * K + bk + c] = f2bf(t[c][r + i * 8]);
}

__global__ __launch_bounds__(256) void prep_kernel(
    const float* __restrict__ qkv_w, const float* __restrict__ proj_w,
    const float* __restrict__ w1, const float* __restrict__ w2,
    unsigned short* __restrict__ qkvT, unsigned short* __restrict__ prjT,
    unsigned short* __restrict__ w1T, unsigned short* __restrict__ w2T,
    const float* __restrict__ table, const int* __restrict__ relidx,
    float* __restrict__ bexp)
{
    __shared__ float t[32][33];
    const int b = blockIdx.x, tid = threadIdx.x;
    if      (b < 192) convT_body(qkv_w, qkvT, 256,  768, b,       t, tid);
    else if (b < 256) convT_body(proj_w, prjT, 256,  256, b - 192, t, tid);
    else if (b < 512) convT_body(w1,    w1T,  256, 1024, b - 256, t, tid);
    else if (b < 768) convT_body(w2,    w2T, 1024,  256, b - 512, t, tid);
    else {
        int i = (b - 768) * 256 + tid;       // 8*64*64 = 32768
        int head = i >> 12;
        int q = (i >> 6) & 63;
        int k = i & 63;
        bexp[i] = table[relidx[q * 64 + k] * 8 + head];
    }
}

// ---- MFMA GEMM: A bf16 [M,K] row-major, BT bf16 [N,K] row-major -----------
// 128x128 tile, 512 threads / 8 waves (wave = 32m x 64n, acc[4][2] = 32 AGPR).
// BK=32 counted-vmcnt dbuf, XCD swizzle, XOR-swizzled LDS, C^T fragments.
template<int OUT_BF16, int DO_GELU, int RESID, int QSCALE>
__global__ __launch_bounds__(512, 4) void mgemm_kernel(
    const unsigned short* __restrict__ A, const unsigned short* __restrict__ BT,
    const float* __restrict__ bias, void* __restrict__ outp,
    const float* __restrict__ resid, int M, int N, int K)
{
    __shared__ unsigned short As[2][128 * 32];
    __shared__ unsigned short Bs[2][128 * 32];

    const int cpx = (int)gridDim.x >> 3;
    const int bid = ((int)blockIdx.x & 7) * cpx + ((int)blockIdx.x >> 3);

    const int nb = N >> 7;
    const int m0 = (bid / nb) << 7;
    const int n0 = (bid % nb) << 7;
    const int tid  = threadIdx.x;
    const int wid  = tid >> 6;
    const int lane = tid & 63;
    const int wm = (wid >> 1) << 5;        // 0,32,64,96
    const int wn = (wid & 1) << 6;         // 0,64

    const unsigned short* Ag = A  + (size_t)m0 * K;
    const unsigned short* Bg = BT + (size_t)n0 * K;
    // 512 slots of 8 shorts cover one 128x32 buffer; slot s holds logical
    // k-group (s&3)^(row&3): pre-swizzled source address
    const size_t ra = (size_t)(tid >> 2) * K + (((tid & 3) ^ ((tid >> 2) & 3)) << 3);

    f32x4 acc[4][2] = {};          // acc[j][i] = C^T fragment (j: n, i: m)
    const int fr = lane & 15;
    const int fq = lane >> 4;
    const int axor = ((fq ^ (fr & 3)) << 3);   // swizzled read offset (elements)

#define STAGE(buf, kk)                                                        \
    {                                                                         \
        gload16(Ag + ra + (kk), As[buf] + tid * 8);                           \
        gload16(Bg + ra + (kk), Bs[buf] + tid * 8);                           \
    }

    // prologue: fill both buffers, wait only for buf0 (2 newest stay in flight)
    STAGE(0, 0);
    STAGE(1, 32);
    asm volatile("s_waitcnt vmcnt(2)" ::: "memory");
    __builtin_amdgcn_s_barrier();
    __builtin_amdgcn_sched_barrier(0);

    for (int k0 = 0; k0 < K; k0 += 32) {
        const int cur = (k0 >> 5) & 1;
        bf16x8 af[2], bfr[4];
#pragma unroll
        for (int i = 0; i < 2; ++i)
            af[i] = *(const bf16x8*)(As[cur] + (wm + i * 16 + fr) * 32 + axor);
#pragma unroll
        for (int j = 0; j < 4; ++j)
            bfr[j] = *(const bf16x8*)(Bs[cur] + (wn + j * 16 + fr) * 32 + axor);
#pragma unroll
        for (int j = 0; j < 4; ++j)
#pragma unroll
            for (int i = 0; i < 2; ++i)
                acc[j][i] = __builtin_amdgcn_mfma_f32_16x16x32_bf16(
                    bfr[j], af[i], acc[j][i], 0, 0, 0);   // C^T: operands swapped

        if (k0 + 32 < K) {
            __builtin_amdgcn_s_barrier();   // all waves done reading buf[cur]
            if (k0 + 64 < K) {
                STAGE(cur, k0 + 64);        // refill the buffer just consumed
                asm volatile("s_waitcnt vmcnt(2)" ::: "memory"); // next buf landed
            } else {
                asm volatile("s_waitcnt vmcnt(0)" ::: "memory"); // last buf landed
            }
            __builtin_amdgcn_s_barrier();
            __builtin_amdgcn_sched_barrier(0);
        }
    }
#undef STAGE

    // epilogue: lane -> row m0+wm+i*16+fr, cols colbase..colbase+3
#pragma unroll
    for (int j = 0; j < 4; ++j) {
        const int colbase = n0 + wn + j * 16 + (fq << 2);
        const float4 b4 = *(const float4*)(bias + colbase);
#pragma unroll
        for (int i = 0; i < 2; ++i) {
            const int row = m0 + wm + i * 16 + fr;
            float v0 = acc[j][i][0] + b4.x;
            float v1 = acc[j][i][1] + b4.y;
            float v2 = acc[j][i][2] + b4.z;
            float v3 = acc[j][i][3] + b4.w;
            if (QSCALE && colbase < 256) {   // colbase%4==0: group never straddles 256
                v0 *= 0.17677669529663687f; v1 *= 0.17677669529663687f;
                v2 *= 0.17677669529663687f; v3 *= 0.17677669529663687f;
            }
            if (DO_GELU) {
                v0 = gelu_f(v0); v1 = gelu_f(v1); v2 = gelu_f(v2); v3 = gelu_f(v3);
            }
            if (OUT_BF16) {
                uint2 pp;
                pp.x = cvtpk_bf16(v0, v1);
                pp.y = cvtpk_bf16(v2, v3);
                *(uint2*)((unsigned short*)outp + (size_t)row * N + colbase) = pp;
            } else {
                const int orow = (RESID == 2) ? remap_row(row) : row;
                float4 o4;
                if (RESID) {
                    const float4 r4 = *(const float4*)(resid + (size_t)orow * N + colbase);
                    o4.x = v0 + r4.x; o4.y = v1 + r4.y;
                    o4.z = v2 + r4.z; o4.w = v3 + r4.w;
                } else {
                    o4.x = v0; o4.y = v1; o4.z = v2; o4.w = v3;
                }
                *(float4*)((float*)outp + (size_t)orow * N + colbase) = o4;
            }
        }
    }
}

// ---- MFMA window attention: one wave per (window, head) -------------------
__global__ __launch_bounds__(64, 3) void attn_kernel(
    const unsigned short* __restrict__ qkv,
    const float* __restrict__ bexp,
    unsigned short* __restrict__ out)
{
    __shared__ unsigned short VT[2048];
    const int bid  = blockIdx.x;
    const int widx = bid & 1023;
    const int head = bid >> 10;
    const int l  = threadIdx.x;
    const int lo = l & 31, hi = l >> 5;

    const unsigned short* base = qkv + (size_t)widx * 64 * 768;

#pragma unroll
    for (int c = 0; c < 4; ++c) {
        union { bf16x8 v; unsigned short s[8]; } u;
        u.v = *(const bf16x8*)(base + (size_t)l * 768 + 512 + head * 32 + c * 8);
#pragma unroll
        for (int e = 0; e < 8; ++e) {
            int d = c * 8 + e;
            int wb = ((d * 64 + l) * 2) ^ ((d & 7) << 4);
            *(unsigned short*)((char*)VT + wb) = u.s[e];
        }
    }

    f32x16 acc[2][2] = {};
#pragma unroll
    for (int kd = 0; kd < 2; ++kd) {
        const int coff = head * 32 + kd * 16 + hi * 8;
        bf16x8 kf0 = *(const bf16x8*)(base + (size_t)lo        * 768 + 256 + coff);
        bf16x8 kf1 = *(const bf16x8*)(base + (size_t)(32 + lo) * 768 + 256 + coff);
        bf16x8 qf0 = *(const bf16x8*)(base + (size_t)lo        * 768 + coff);
        bf16x8 qf1 = *(const bf16x8*)(base + (size_t)(32 + lo) * 768 + coff);
        acc[0][0] = __builtin_amdgcn_mfma_f32_32x32x16_bf16(kf0, qf0, acc[0][0], 0, 0, 0);
        acc[0][1] = __builtin_amdgcn_mfma_f32_32x32x16_bf16(kf0, qf1, acc[0][1], 0, 0, 0);
        acc[1][0] = __builtin_amdgcn_mfma_f32_32x32x16_bf16(kf1, qf0, acc[1][0], 0, 0, 0);
        acc[1][1] = __builtin_amdgcn_mfma_f32_32x32x16_bf16(kf1, qf1, acc[1][1], 0, 0, 0);
    }

#pragma unroll
    for (int qb = 0; qb < 2; ++qb) {
        const float* bq = bexp + head * 4096 + (qb * 32 + lo) * 64;
#pragma unroll
        for (int kb = 0; kb < 2; ++kb)
#pragma unroll
            for (int j = 0; j < 4; ++j) {
                float4 b4 = *(const float4*)(bq + kb * 32 + j * 8 + hi * 4);
                acc[kb][qb][4 * j + 0] += b4.x;
                acc[kb][qb][4 * j + 1] += b4.y;
                acc[kb][qb][4 * j + 2] += b4.z;
                acc[kb][qb][4 * j + 3] += b4.w;
            }
    }

    const int w6 = widx & 63;
    if (((w6 >> 3) == 7) || ((w6 & 7) == 7)) {
#pragma unroll
        for (int qb = 0; qb < 2; ++qb) {
            int nq = qb * 32 + lo;
            int phq = ((w6 >> 3) << 3) + (nq >> 3), pwq = ((w6 & 7) << 3) + (nq & 7);
            int rq = ((phq < 56) ? 0 : ((phq < 60) ? 1 : 2)) * 3
                   + ((pwq < 56) ? 0 : ((pwq < 60) ? 1 : 2));
#pragma unroll
            for (int kb = 0; kb < 2; ++kb)
#pragma unroll
                for (int r = 0; r < 16; ++r) {
                    int nk = kb * 32 + (r & 3) + 8 * (r >> 2) + 4 * hi;
                    int phk = ((w6 >> 3) << 3) + (nk >> 3), pwk = ((w6 & 7) << 3) + (nk & 7);
                    int rk = ((phk < 56) ? 0 : ((phk < 60) ? 1 : 2)) * 3
                           + ((pwk < 56) ? 0 : ((pwk < 60) ? 1 : 2));
                    if (rk != rq) acc[kb][qb][r] -= 100.0f;
                }
        }
    }

#pragma unroll
    for (int qb = 0; qb < 2; ++qb) {
        float mx = acc[0][qb][0];
#pragma unroll
        for (int r = 1; r < 16; ++r) mx = fmaxf(mx, acc[0][qb][r]);
#pragma unroll
        for (int r = 0; r < 16; ++r) mx = fmaxf(mx, acc[1][qb][r]);
        mx = fmaxf(mx, __shfl_xor(mx, 32, 64));
        float sum = 0.f;
#pragma unroll
        for (int kb = 0; kb < 2; ++kb)
#pragma unroll
            for (int r = 0; r < 16; ++r) {
                float e = __expf(acc[kb][qb][r] - mx);
                acc[kb][qb][r] = e;
                sum += e;
            }
        sum += __shfl_xor(sum, 32, 64);
        float inv = 1.0f / sum;
#pragma unroll
        for (int kb = 0; kb < 2; ++kb)
#pragma unroll
            for (int r = 0; r < 16; ++r) acc[kb][qb][r] *= inv;
    }

    f32x16 o[2] = {};
#pragma unroll
    for (int ks = 0; ks < 4; ++ks) {
        const int s8 = (ks & 1) * 8, kb = ks >> 1;
        const int rb = ((lo * 64 + 16 * ks + 8 * hi) * 2) ^ ((lo & 7) << 4);
        bf16x8 vb = *(const bf16x8*)((const char*)VT + rb);
#pragma unroll
        for (int qb = 0; qb < 2; ++qb) {
            unsigned int a0 = cvtpk_bf16(acc[kb][qb][s8 + 0], acc[kb][qb][s8 + 1]);
            unsigned int b0 = cvtpk_bf16(acc[kb][qb][s8 + 4], acc[kb][qb][s8 + 5]);
            unsigned int a1 = cvtpk_bf16(acc[kb][qb][s8 + 2], acc[kb][qb][s8 + 3]);
            unsigned int b1 = cvtpk_bf16(acc[kb][qb][s8 + 6], acc[kb][qb][s8 + 7]);
            perm32swap(a0, b0);
            perm32swap(a1, b1);
            union { unsigned int u[4]; bf16x8 v; } w;
            w.u[0] = a0; w.u[1] = a1; w.u[2] = b0; w.u[3] = b1;
            o[qb] = __builtin_amdgcn_mfma_f32_32x32x16_bf16(w.v, vb, o[qb], 0, 0, 0);
        }
    }

    unsigned short* ob = out + (size_t)widx * 64 * 256 + head * 32 + lo;
#pragma unroll
    for (int qb = 0; qb < 2; ++qb)
#pragma unroll
        for (int r = 0; r < 16; ++r) {
            int q = qb * 32 + (r & 3) + 8 * (r >> 2) + 4 * hi;
            ob[(size_t)q * 256] = f2bf(o[qb][r]);
        }
}

// ---------------------------------------------------------------------------
extern "C" void kernel_launch(void* const* d_in, const int* in_sizes, int n_in,
                              void* d_out, int out_size, void* d_ws, size_t ws_size,
                              hipStream_t stream)
{
    const float* x      = (const float*)d_in[0];
    const float* ln1_g  = (const float*)d_in[1];
    const float* ln1_b  = (const float*)d_in[2];
    const float* qkv_w  = (const float*)d_in[3];
    const float* qkv_b  = (const float*)d_in[4];
    const float* proj_w = (const float*)d_in[5];
    const float* proj_b = (const float*)d_in[6];
    const float* table  = (const float*)d_in[7];
    const float* ln2_g  = (const float*)d_in[8];
    const float* ln2_b  = (const float*)d_in[9];
    const float* w1     = (const float*)d_in[10];
    const float* b1     = (const float*)d_in[11];
    const float* w2     = (const float*)d_in[12];
    const float* b2     = (const float*)d_in[13];
    const int*   relidx = (const int*)d_in[14];
    float* out = (float*)d_out;

    char* w = (char*)d_ws;
    unsigned short* xw   = (unsigned short*)w;                      // 32MB (xw -> attn_out -> ln2out)
    unsigned short* qkvb = (unsigned short*)(w + (32u << 20));      // 128MB (qkv 96MB -> mlp hidden 128MB)
    float*          h2   = (float*)(w + (160u << 20));              // 64MB
    float*          bexp = (float*)(w + (224u << 20));              // 128KB
    unsigned short* qkvT = (unsigned short*)(w + (224u << 20) + (128u << 10)); // 384KB
    unsigned short* prjT = qkvT + 768 * 256;                        // 128KB
    unsigned short* w1T  = prjT + 256 * 256;                        // 512KB
    unsigned short* w2T  = w1T + 1024 * 256;                        // 512KB

    // 0. weight transposes + bf16 convert + rel-pos bias expand (one kernel)
    prep_kernel<<<896, 256, 0, stream>>>(qkv_w, proj_w, w1, w2,
                                         qkvT, prjT, w1T, w2T,
                                         table, relidx, bexp);
    // 1. LN1 + cyclic shift + window partition (gather) -> xw bf16 [65536,256]
    ln_kernel<<<16384, 256, 0, stream>>>(x, ln1_g, ln1_b, xw, 1);
    // 2. QKV GEMM (q cols pre-scaled by hd^-0.5) -> qkvb bf16 [65536,768]
    mgemm_kernel<1, 0, 0, 1><<<512 * 6, 512, 0, stream>>>(xw, qkvT, qkv_b, (void*)qkvb,
                                                          nullptr, 65536, 768, 256);
    // 3. MFMA window attention -> attn_out (reuse xw) bf16 [65536,256]
    attn_kernel<<<8192, 64, 0, stream>>>(qkvb, bexp, xw);
    // 4. proj GEMM + window-reverse/unshift scatter + residual(x) -> h2 f32
    mgemm_kernel<0, 0, 2, 0><<<512 * 2, 512, 0, stream>>>(xw, prjT, proj_b, (void*)h2,
                                                          x, 65536, 256, 256);
    // 5. LN2 -> ln2out (reuse xw) bf16
    ln_kernel<<<16384, 256, 0, stream>>>(h2, ln2_g, ln2_b, xw, 0);
    // 6. MLP1 GEMM + GELU -> hidden (reuse qkvb) bf16 [65536,1024]
    mgemm_kernel<1, 1, 0, 0><<<512 * 8, 512, 0, stream>>>(xw, w1T, b1, (void*)qkvb,
                                                          nullptr, 65536, 1024, 256);
    // 7. MLP2 GEMM + residual(h2) -> d_out f32
    mgemm_kernel<0, 0, 1, 0><<<512 * 2, 512, 0, stream>>>(qkvb, w2T, b2, (void*)out,
                                                          h2, 65536, 256, 1024);
}